// Round 2
// baseline (3728.415 us; speedup 1.0000x reference)
//
#include <hip/hip_runtime.h>
#include <cstdint>

#define NPTS 8192
#define NBATCH 4
#define NS 2048
#define NK 32
#define CIN 64
#define C0 67   // 3 + 64
#define H1 64
#define H2 64
#define H3 128
#define CAP 1024
#define BIGF 1e10f

// ws layout in floats
#define WT0_OFF 0        // 67*64
#define B0_OFF  4288     // 64
#define WT1_OFF 4352     // 64*64
#define B1_OFF  8448     // 64
#define WT2_OFF 8512     // 64*128
#define B2_OFF  16704    // 128
#define FPS_OFF 16832    // NBATCH*NS ints from here

__device__ __forceinline__ float sq3(float ax, float ay, float az) {
  // exact f32, no contraction: (ax*ax + ay*ay) + az*az
  return __fadd_rn(__fadd_rn(__fmul_rn(ax, ax), __fmul_rn(ay, ay)), __fmul_rn(az, az));
}

// ---------------- fold BN into weights (transposed [c][o]) ----------------
__global__ void fold_kernel(const float* __restrict__ W0, const float* __restrict__ g0, const float* __restrict__ be0, const float* __restrict__ m0, const float* __restrict__ v0,
                            const float* __restrict__ W1, const float* __restrict__ g1, const float* __restrict__ be1, const float* __restrict__ m1, const float* __restrict__ v1,
                            const float* __restrict__ W2, const float* __restrict__ g2, const float* __restrict__ be2, const float* __restrict__ m2, const float* __restrict__ v2,
                            float* __restrict__ ws) {
  int t = blockIdx.x * 256 + threadIdx.x;
  if (t < C0 * H1) {
    int c = t / H1, o = t - c * H1;
    float sc = g0[o] / sqrtf(v0[o] + 1e-5f);
    ws[WT0_OFF + t] = W0[o * C0 + c] * sc;
  } else if (t < B0_OFF + H1) {
    int o = t - B0_OFF;
    float sc = g0[o] / sqrtf(v0[o] + 1e-5f);
    ws[t] = be0[o] - m0[o] * sc;
  } else if (t < WT1_OFF + H1 * H2) {
    int t2 = t - WT1_OFF; int c = t2 / H2, o = t2 - c * H2;
    float sc = g1[o] / sqrtf(v1[o] + 1e-5f);
    ws[t] = W1[o * H1 + c] * sc;
  } else if (t < B1_OFF + H2) {
    int o = t - B1_OFF;
    float sc = g1[o] / sqrtf(v1[o] + 1e-5f);
    ws[t] = be1[o] - m1[o] * sc;
  } else if (t < WT2_OFF + H2 * H3) {
    int t2 = t - WT2_OFF; int c = t2 / H3, o = t2 - c * H3;
    float sc = g2[o] / sqrtf(v2[o] + 1e-5f);
    ws[t] = W2[o * H2 + c] * sc;
  } else if (t < B2_OFF + H3) {
    int o = t - B2_OFF;
    float sc = g2[o] / sqrtf(v2[o] + 1e-5f);
    ws[t] = be2[o] - m2[o] * sc;
  }
}

// ---------------- FPS: one block per batch, 1024 threads, 8 pts/thread ----------------
__global__ __launch_bounds__(1024)
void fps_kernel(const float* __restrict__ xyz, float* __restrict__ newxyz, int* __restrict__ fpsidx) {
  const int b = blockIdx.x;
  const float* px = xyz + (size_t)b * NPTS * 3;
  const int tid = threadIdx.x;

  float X[8], Y[8], Z[8], D[8];
#pragma unroll
  for (int j = 0; j < 8; ++j) {
    int p = tid * 8 + j;
    X[j] = px[p * 3 + 0];
    Y[j] = px[p * 3 + 1];
    Z[j] = px[p * 3 + 2];
    D[j] = BIGF;
  }

  __shared__ float redD[16];
  __shared__ int redI[16];
  __shared__ int farS;

  int far = 0;
  for (int t = 0; t < NS; ++t) {
    if (tid == 0) {
      fpsidx[b * NS + t] = far;
      float* o = newxyz + ((size_t)b * NS + t) * 3;
      o[0] = px[far * 3 + 0];
      o[1] = px[far * 3 + 1];
      o[2] = px[far * 3 + 2];
    }
    if (t == NS - 1) break;

    const float cx = px[far * 3 + 0];
    const float cy = px[far * 3 + 1];
    const float cz = px[far * 3 + 2];

    float bd = -1.0f; int bi = 0;
#pragma unroll
    for (int j = 0; j < 8; ++j) {
      float dx = __fsub_rn(X[j], cx);
      float dy = __fsub_rn(Y[j], cy);
      float dz = __fsub_rn(Z[j], cz);
      float d = sq3(dx, dy, dz);
      float nd = fminf(D[j], d);
      D[j] = nd;
      bool gt = nd > bd;               // strict > keeps lowest index (in-order scan)
      bd = gt ? nd : bd;
      bi = gt ? (tid * 8 + j) : bi;
    }
    // wave argmax, tie -> lower index
#pragma unroll
    for (int m = 1; m < 64; m <<= 1) {
      float od = __shfl_xor(bd, m);
      int oi = __shfl_xor(bi, m);
      bool take = (od > bd) || ((od == bd) && (oi < bi));
      bd = take ? od : bd;
      bi = take ? oi : bi;
    }
    if ((tid & 63) == 0) { redD[tid >> 6] = bd; redI[tid >> 6] = bi; }
    __syncthreads();
    if (tid < 64) {
      float vd = (tid < 16) ? redD[tid] : -1.0f;
      int vi = (tid < 16) ? redI[tid] : 0;
#pragma unroll
      for (int m = 1; m < 16; m <<= 1) {
        float od = __shfl_xor(vd, m);
        int oi = __shfl_xor(vi, m);
        bool take = (od > vd) || ((od == vd) && (oi < vi));
        vd = take ? od : vd;
        vi = take ? oi : vi;
      }
      if (tid == 0) farS = vi;
    }
    __syncthreads();
    far = farS;
  }
}

// ---------------- ball query + group + MLP + maxpool: one block per centroid ----------------
__global__ __launch_bounds__(256)
void sa_kernel(const float* __restrict__ xyz, const float* __restrict__ feat,
               const float* __restrict__ ws, const int* __restrict__ fpsidx,
               const float* __restrict__ newxyz, float* __restrict__ outf) {
  const int bs = blockIdx.x;
  const int b = bs >> 11;
  const int s = bs & (NS - 1);
  const int tid = threadIdx.x;

  __shared__ unsigned long long cand[CAP];
  __shared__ int cntS;
  __shared__ int sel[NK];
  __shared__ float hA[32 * 69];
  __shared__ float hB[32 * 65];

  const float* px = xyz + (size_t)b * NPTS * 3;
  const float* pf = feat + (size_t)b * NPTS * CIN;
  const size_t srow = (size_t)b * NS + s;
  const float cx = newxyz[srow * 3 + 0];
  const float cy = newxyz[srow * 3 + 1];
  const float cz = newxyz[srow * 3 + 2];

  if (tid == 0) cntS = 0;
  __syncthreads();

  // ---- phase A: ball query (reference formula, exact f32, no contraction) ----
  const float ssrc = sq3(cx, cy, cz);
  const float R2F = 0.04f;  // f32 round of f64 0.2**2 (NOT 0.2f*0.2f — 1 ulp above)
  for (int p = tid; p < NPTS; p += 256) {
    float x = px[p * 3 + 0], y = px[p * 3 + 1], z = px[p * 3 + 2];
    float sdst = sq3(x, y, z);
    float dot = __fadd_rn(__fadd_rn(__fmul_rn(cx, x), __fmul_rn(cy, y)), __fmul_rn(cz, z));
    float d = __fsub_rn(__fadd_rn(ssrc, sdst), __fmul_rn(2.0f, dot));
    d = fmaxf(d, 0.0f);
    if (d <= R2F) {
      int pos = atomicAdd(&cntS, 1);
      if (pos < CAP) cand[pos] = ((unsigned long long)__float_as_uint(d) << 32) | (unsigned long long)(unsigned)p;
    }
  }
  __syncthreads();

  // ---- phase B: select 32 smallest (tie -> lower point index) by wave 0 ----
  if (tid < 64) {
    const int cnt = min(cntS, CAP);
    unsigned long long key[CAP / 64];
#pragma unroll
    for (int r = 0; r < CAP / 64; ++r) {
      int e = r * 64 + tid;
      key[r] = (e < cnt) ? cand[e] : ~0ull;
    }
    unsigned long long thr = 0ull;  // keys are unique; extract in strictly increasing order
    int firstidx = 0;
    for (int j = 0; j < NK; ++j) {
      unsigned long long bk = ~0ull;
#pragma unroll
      for (int r = 0; r < CAP / 64; ++r) {
        unsigned long long kk = key[r];
        bool ok = (kk >= thr) && (kk < bk);
        bk = ok ? kk : bk;
      }
#pragma unroll
      for (int m = 1; m < 64; m <<= 1) {
        unsigned long long o = __shfl_xor(bk, m);
        bk = (o < bk) ? o : bk;
      }
      if (j == 0) firstidx = (int)(bk & 0xffffffffull);
      int idx = (bk == ~0ull) ? firstidx : (int)(bk & 0xffffffffull);  // pad with nearest (ref semantics)
      if (tid == 0) sel[j] = idx;
      if (bk != ~0ull) thr = bk + 1ull;
    }
  }
  __syncthreads();

  // ---- phase C: build h0 = [centered xyz(3) | feat(64)] into hA [32][69] ----
  {
    int kk = tid >> 3, j = tid & 7;
    int ip = sel[kk];
    const float* fr = pf + (size_t)ip * CIN + j * 8;
    float4 a = *(const float4*)(fr);
    float4 c4 = *(const float4*)(fr + 4);
    float* hrow = hA + kk * 69 + 3 + j * 8;
    hrow[0] = a.x;  hrow[1] = a.y;  hrow[2] = a.z;  hrow[3] = a.w;
    hrow[4] = c4.x; hrow[5] = c4.y; hrow[6] = c4.z; hrow[7] = c4.w;
  }
  if (tid < 32) {
    int ip = sel[tid];
    hA[tid * 69 + 0] = px[ip * 3 + 0] - cx;
    hA[tid * 69 + 1] = px[ip * 3 + 1] - cy;
    hA[tid * 69 + 2] = px[ip * 3 + 2] - cz;
  }
  __syncthreads();

  const int k = tid & 31;   // neighbor slot
  const int ob = tid >> 5;  // output-channel block (0..7)

  // ---- layer 1: 67 -> 64 ----
  {
    const float* Wt = ws + WT0_OFF;
    const float* bb = ws + B0_OFF;
    const int o0 = ob * 8;
    float acc[8];
#pragma unroll
    for (int i = 0; i < 8; ++i) acc[i] = bb[o0 + i];
    const float* hrow = hA + k * 69;
    for (int c = 0; c < C0; ++c) {
      float h = hrow[c];
      const float4 w0 = *(const float4*)(Wt + c * H1 + o0);
      const float4 w1 = *(const float4*)(Wt + c * H1 + o0 + 4);
      acc[0] = fmaf(h, w0.x, acc[0]); acc[1] = fmaf(h, w0.y, acc[1]);
      acc[2] = fmaf(h, w0.z, acc[2]); acc[3] = fmaf(h, w0.w, acc[3]);
      acc[4] = fmaf(h, w1.x, acc[4]); acc[5] = fmaf(h, w1.y, acc[5]);
      acc[6] = fmaf(h, w1.z, acc[6]); acc[7] = fmaf(h, w1.w, acc[7]);
    }
    float* orow = hB + k * 65 + o0;
#pragma unroll
    for (int i = 0; i < 8; ++i) orow[i] = fmaxf(acc[i], 0.0f);
  }
  __syncthreads();

  // ---- layer 2: 64 -> 64 (hB -> hA, stride 65) ----
  {
    const float* Wt = ws + WT1_OFF;
    const float* bb = ws + B1_OFF;
    const int o0 = ob * 8;
    float acc[8];
#pragma unroll
    for (int i = 0; i < 8; ++i) acc[i] = bb[o0 + i];
    const float* hrow = hB + k * 65;
    for (int c = 0; c < H1; ++c) {
      float h = hrow[c];
      const float4 w0 = *(const float4*)(Wt + c * H2 + o0);
      const float4 w1 = *(const float4*)(Wt + c * H2 + o0 + 4);
      acc[0] = fmaf(h, w0.x, acc[0]); acc[1] = fmaf(h, w0.y, acc[1]);
      acc[2] = fmaf(h, w0.z, acc[2]); acc[3] = fmaf(h, w0.w, acc[3]);
      acc[4] = fmaf(h, w1.x, acc[4]); acc[5] = fmaf(h, w1.y, acc[5]);
      acc[6] = fmaf(h, w1.z, acc[6]); acc[7] = fmaf(h, w1.w, acc[7]);
    }
    float* orow = hA + k * 65 + o0;
#pragma unroll
    for (int i = 0; i < 8; ++i) orow[i] = fmaxf(acc[i], 0.0f);
  }
  __syncthreads();

  // ---- layer 3: 64 -> 128 + max over neighbors ----
  {
    const float* Wt = ws + WT2_OFF;
    const float* bb = ws + B2_OFF;
    const int o0 = ob * 16;
    float acc[16];
#pragma unroll
    for (int i = 0; i < 16; ++i) acc[i] = bb[o0 + i];
    const float* hrow = hA + k * 65;
    for (int c = 0; c < H2; ++c) {
      float h = hrow[c];
      const float4 w0 = *(const float4*)(Wt + c * H3 + o0);
      const float4 w1 = *(const float4*)(Wt + c * H3 + o0 + 4);
      const float4 w2 = *(const float4*)(Wt + c * H3 + o0 + 8);
      const float4 w3 = *(const float4*)(Wt + c * H3 + o0 + 12);
      acc[0]  = fmaf(h, w0.x, acc[0]);  acc[1]  = fmaf(h, w0.y, acc[1]);
      acc[2]  = fmaf(h, w0.z, acc[2]);  acc[3]  = fmaf(h, w0.w, acc[3]);
      acc[4]  = fmaf(h, w1.x, acc[4]);  acc[5]  = fmaf(h, w1.y, acc[5]);
      acc[6]  = fmaf(h, w1.z, acc[6]);  acc[7]  = fmaf(h, w1.w, acc[7]);
      acc[8]  = fmaf(h, w2.x, acc[8]);  acc[9]  = fmaf(h, w2.y, acc[9]);
      acc[10] = fmaf(h, w2.z, acc[10]); acc[11] = fmaf(h, w2.w, acc[11]);
      acc[12] = fmaf(h, w3.x, acc[12]); acc[13] = fmaf(h, w3.y, acc[13]);
      acc[14] = fmaf(h, w3.z, acc[14]); acc[15] = fmaf(h, w3.w, acc[15]);
    }
#pragma unroll
    for (int i = 0; i < 16; ++i) acc[i] = fmaxf(acc[i], 0.0f);
    // max over 32 neighbor slots (lanes differing in bits 0..4)
#pragma unroll
    for (int m = 1; m < 32; m <<= 1) {
#pragma unroll
      for (int i = 0; i < 16; ++i) {
        float o = __shfl_xor(acc[i], m);
        acc[i] = fmaxf(acc[i], o);
      }
    }
    if (k == 0) {
      float* op = outf + srow * H3 + o0;
      *(float4*)(op + 0)  = make_float4(acc[0],  acc[1],  acc[2],  acc[3]);
      *(float4*)(op + 4)  = make_float4(acc[4],  acc[5],  acc[6],  acc[7]);
      *(float4*)(op + 8)  = make_float4(acc[8],  acc[9],  acc[10], acc[11]);
      *(float4*)(op + 12) = make_float4(acc[12], acc[13], acc[14], acc[15]);
    }
  }
}

extern "C" void kernel_launch(void* const* d_in, const int* in_sizes, int n_in,
                              void* d_out, int out_size, void* d_ws, size_t ws_size,
                              hipStream_t stream) {
  const float* xyz  = (const float*)d_in[0];
  const float* feat = (const float*)d_in[1];
  const float* W0 = (const float*)d_in[2];
  const float* g0 = (const float*)d_in[3];
  const float* be0 = (const float*)d_in[4];
  const float* m0 = (const float*)d_in[5];
  const float* v0 = (const float*)d_in[6];
  const float* W1 = (const float*)d_in[7];
  const float* g1 = (const float*)d_in[8];
  const float* be1 = (const float*)d_in[9];
  const float* m1 = (const float*)d_in[10];
  const float* v1 = (const float*)d_in[11];
  const float* W2 = (const float*)d_in[12];
  const float* g2 = (const float*)d_in[13];
  const float* be2 = (const float*)d_in[14];
  const float* m2 = (const float*)d_in[15];
  const float* v2 = (const float*)d_in[16];

  float* out = (float*)d_out;               // [B,S,3] then [B,S,128]
  float* ws = (float*)d_ws;
  int* fpsidx = (int*)(ws + FPS_OFF);
  float* outfeat = out + (size_t)NBATCH * NS * 3;

  fold_kernel<<<(B2_OFF + H3 + 255) / 256, 256, 0, stream>>>(
      W0, g0, be0, m0, v0, W1, g1, be1, m1, v1, W2, g2, be2, m2, v2, ws);
  fps_kernel<<<NBATCH, 1024, 0, stream>>>(xyz, out, fpsidx);
  sa_kernel<<<NBATCH * NS, 256, 0, stream>>>(xyz, feat, ws, fpsidx, out, outfeat);
}

// Round 4
// 3465.673 us; speedup vs baseline: 1.0758x; 1.0758x over previous
//
#include <hip/hip_runtime.h>
#include <cstdint>

#define NPTS 8192
#define NBATCH 4
#define NS 2048
#define NK 32
#define CIN 64
#define C0 67   // 3 + 64
#define H1 64
#define H2 64
#define H3 128
#define CAP 1024
#define BIGF 1e10f

// ws layout in floats
#define WT0_OFF 0        // 67*64
#define B0_OFF  4288     // 64
#define WT1_OFF 4352     // 64*64
#define B1_OFF  8448     // 64
#define WT2_OFF 8512     // 64*128
#define B2_OFF  16704    // 128
#define FPS_OFF 16832    // NBATCH*NS ints from here

__device__ __forceinline__ float sq3(float ax, float ay, float az) {
  // exact f32, no contraction: (ax*ax + ay*ay) + az*az
  return __fadd_rn(__fadd_rn(__fmul_rn(ax, ax), __fmul_rn(ay, ay)), __fmul_rn(az, az));
}

// ---------------- fold BN into weights (transposed [c][o]) ----------------
__global__ void fold_kernel(const float* __restrict__ W0, const float* __restrict__ g0, const float* __restrict__ be0, const float* __restrict__ m0, const float* __restrict__ v0,
                            const float* __restrict__ W1, const float* __restrict__ g1, const float* __restrict__ be1, const float* __restrict__ m1, const float* __restrict__ v1,
                            const float* __restrict__ W2, const float* __restrict__ g2, const float* __restrict__ be2, const float* __restrict__ m2, const float* __restrict__ v2,
                            float* __restrict__ ws) {
  int t = blockIdx.x * 256 + threadIdx.x;
  if (t < C0 * H1) {
    int c = t / H1, o = t - c * H1;
    float sc = g0[o] / sqrtf(v0[o] + 1e-5f);
    ws[WT0_OFF + t] = W0[o * C0 + c] * sc;
  } else if (t < B0_OFF + H1) {
    int o = t - B0_OFF;
    float sc = g0[o] / sqrtf(v0[o] + 1e-5f);
    ws[t] = be0[o] - m0[o] * sc;
  } else if (t < WT1_OFF + H1 * H2) {
    int t2 = t - WT1_OFF; int c = t2 / H2, o = t2 - c * H2;
    float sc = g1[o] / sqrtf(v1[o] + 1e-5f);
    ws[t] = W1[o * H1 + c] * sc;
  } else if (t < B1_OFF + H2) {
    int o = t - B1_OFF;
    float sc = g1[o] / sqrtf(v1[o] + 1e-5f);
    ws[t] = be1[o] - m1[o] * sc;
  } else if (t < WT2_OFF + H2 * H3) {
    int t2 = t - WT2_OFF; int c = t2 / H3, o = t2 - c * H3;
    float sc = g2[o] / sqrtf(v2[o] + 1e-5f);
    ws[t] = W2[o * H2 + c] * sc;
  } else if (t < B2_OFF + H3) {
    int o = t - B2_OFF;
    float sc = g2[o] / sqrtf(v2[o] + 1e-5f);
    ws[t] = be2[o] - m2[o] * sc;
  }
}

// ---------------- FPS: one block per batch, 1024 threads, 8 pts/thread ----------------
// One barrier/iter; winner coords travel through LDS (no global centroid reads);
// packed u64 key (distbits<<32 | ~idx) makes max-reduce give first-index ties.
__global__ __launch_bounds__(1024)
void fps_kernel(const float* __restrict__ xyz, float* __restrict__ newxyz, int* __restrict__ fpsidx) {
  const int b = blockIdx.x;
  const float* px = xyz + (size_t)b * NPTS * 3;
  const int tid = threadIdx.x;
  const int lane = tid & 63;
  const int wv = tid >> 6;

  float X[8], Y[8], Z[8], D[8];
#pragma unroll
  for (int j = 0; j < 8; ++j) {
    int p = tid * 8 + j;
    X[j] = px[p * 3 + 0];
    Y[j] = px[p * 3 + 1];
    Z[j] = px[p * 3 + 2];
    D[j] = BIGF;
  }

  __shared__ unsigned long long pK[2][16];
  __shared__ float pX[2][16], pY[2][16], pZ[2][16];

  float cx = px[0], cy = px[1], cz = px[2];
  if (tid == 0) {
    fpsidx[b * NS] = 0;
    float* o = newxyz + (size_t)b * NS * 3;
    o[0] = cx; o[1] = cy; o[2] = cz;
  }

  int par = 0;
  for (int t = 1; t < NS; ++t) {
    // ---- update min-dist (exact f32, reference op order) + per-thread max ----
    float nd[8];
#pragma unroll
    for (int j = 0; j < 8; ++j) {
      float dx = __fsub_rn(X[j], cx);
      float dy = __fsub_rn(Y[j], cy);
      float dz = __fsub_rn(Z[j], cz);
      float d = sq3(dx, dy, dz);
      nd[j] = fminf(D[j], d);
      D[j] = nd[j];
    }
    float bd = fmaxf(fmaxf(fmaxf(nd[0], nd[1]), fmaxf(nd[2], nd[3])),
                     fmaxf(fmaxf(nd[4], nd[5]), fmaxf(nd[6], nd[7])));
    // ---- wave max + winner lane via ballot (lowest lane = lowest index) ----
    float bdw = bd;
#pragma unroll
    for (int m = 1; m < 64; m <<= 1) bdw = fmaxf(bdw, __shfl_xor(bdw, m));
    unsigned long long mk = __ballot(bd == bdw);
    int wl = __ffsll(mk) - 1;
    if (lane == wl) {
      // recover smallest j with nd[j]==bd, and its coords (static indexing only)
      int bj = 7;
      float sx = X[7], sy = Y[7], sz = Z[7];
#pragma unroll
      for (int j = 6; j >= 0; --j) {
        bool e = (nd[j] == bd);
        bj = e ? j : bj;
        sx = e ? X[j] : sx;
        sy = e ? Y[j] : sy;
        sz = e ? Z[j] : sz;
      }
      unsigned bi = (unsigned)(tid * 8 + bj);
      pK[par][wv] = ((unsigned long long)__float_as_uint(bd) << 32) | (unsigned long long)(~bi);
      pX[par][wv] = sx; pY[par][wv] = sy; pZ[par][wv] = sz;
    }
    __syncthreads();
    // ---- all waves redundantly reduce the 16 wave-candidates ----
    unsigned long long k = pK[par][lane & 15];
#pragma unroll
    for (int m = 1; m < 16; m <<= 1) {
      unsigned long long o = __shfl_xor(k, m);
      k = (o > k) ? o : k;
    }
    const int far = (int)(~(unsigned)k);
    const int ww = far >> 9;  // 512 points per wave
    cx = pX[par][ww]; cy = pY[par][ww]; cz = pZ[par][ww];
    par ^= 1;
    if (tid == 0) {
      fpsidx[b * NS + t] = far;
      float* o = newxyz + ((size_t)b * NS + t) * 3;
      o[0] = cx; o[1] = cy; o[2] = cz;
    }
  }
}

// ---------------- ball query + group + MLP + maxpool: one block per centroid ----------------
__global__ __launch_bounds__(256)
void sa_kernel(const float* __restrict__ xyz, const float* __restrict__ feat,
               const float* __restrict__ ws, const int* __restrict__ fpsidx,
               const float* __restrict__ newxyz, float* __restrict__ outf) {
  const int bs = blockIdx.x;
  const int b = bs >> 11;
  const int s = bs & (NS - 1);
  const int tid = threadIdx.x;

  __shared__ unsigned long long cand[CAP];
  __shared__ int cntS;
  __shared__ int sel[NK];
  __shared__ float hA[32 * 69];
  __shared__ float hB[32 * 65];

  const float* px = xyz + (size_t)b * NPTS * 3;
  const float* pf = feat + (size_t)b * NPTS * CIN;
  const size_t srow = (size_t)b * NS + s;
  const float cx = newxyz[srow * 3 + 0];
  const float cy = newxyz[srow * 3 + 1];
  const float cz = newxyz[srow * 3 + 2];

  if (tid == 0) cntS = 0;
  __syncthreads();

  // ---- phase A: ball query (reference formula, exact f32, no contraction) ----
  const float ssrc = sq3(cx, cy, cz);
  const float R2F = 0.04f;  // f32 round of f64 0.2**2 (NOT 0.2f*0.2f — 1 ulp above)
  for (int p = tid; p < NPTS; p += 256) {
    float x = px[p * 3 + 0], y = px[p * 3 + 1], z = px[p * 3 + 2];
    float sdst = sq3(x, y, z);
    float dot = __fadd_rn(__fadd_rn(__fmul_rn(cx, x), __fmul_rn(cy, y)), __fmul_rn(cz, z));
    float d = __fsub_rn(__fadd_rn(ssrc, sdst), __fmul_rn(2.0f, dot));
    d = fmaxf(d, 0.0f);
    if (d <= R2F) {
      int pos = atomicAdd(&cntS, 1);
      if (pos < CAP) cand[pos] = ((unsigned long long)__float_as_uint(d) << 32) | (unsigned long long)(unsigned)p;
    }
  }
  __syncthreads();

  // ---- phase B: select 32 smallest (tie -> lower point index) by wave 0 ----
  if (tid < 64) {
    const int cnt = min(cntS, CAP);
    unsigned long long key[CAP / 64];
#pragma unroll
    for (int r = 0; r < CAP / 64; ++r) {
      int e = r * 64 + tid;
      key[r] = (e < cnt) ? cand[e] : ~0ull;
    }
    unsigned long long thr = 0ull;  // keys are unique; extract in strictly increasing order
    int firstidx = 0;
    for (int j = 0; j < NK; ++j) {
      unsigned long long bk = ~0ull;
#pragma unroll
      for (int r = 0; r < CAP / 64; ++r) {
        unsigned long long kk = key[r];
        bool ok = (kk >= thr) && (kk < bk);
        bk = ok ? kk : bk;
      }
#pragma unroll
      for (int m = 1; m < 64; m <<= 1) {
        unsigned long long o = __shfl_xor(bk, m);
        bk = (o < bk) ? o : bk;
      }
      if (j == 0) firstidx = (int)(bk & 0xffffffffull);
      int idx = (bk == ~0ull) ? firstidx : (int)(bk & 0xffffffffull);  // pad with nearest (ref semantics)
      if (tid == 0) sel[j] = idx;
      if (bk != ~0ull) thr = bk + 1ull;
    }
  }
  __syncthreads();

  // ---- phase C: build h0 = [centered xyz(3) | feat(64)] into hA [32][69] ----
  {
    int kk = tid >> 3, j = tid & 7;
    int ip = sel[kk];
    const float* fr = pf + (size_t)ip * CIN + j * 8;
    float4 a = *(const float4*)(fr);
    float4 c4 = *(const float4*)(fr + 4);
    float* hrow = hA + kk * 69 + 3 + j * 8;
    hrow[0] = a.x;  hrow[1] = a.y;  hrow[2] = a.z;  hrow[3] = a.w;
    hrow[4] = c4.x; hrow[5] = c4.y; hrow[6] = c4.z; hrow[7] = c4.w;
  }
  if (tid < 32) {
    int ip = sel[tid];
    hA[tid * 69 + 0] = px[ip * 3 + 0] - cx;
    hA[tid * 69 + 1] = px[ip * 3 + 1] - cy;
    hA[tid * 69 + 2] = px[ip * 3 + 2] - cz;
  }
  __syncthreads();

  const int k = tid & 31;   // neighbor slot
  const int ob = tid >> 5;  // output-channel block (0..7)

  // ---- layer 1: 67 -> 64 ----
  {
    const float* Wt = ws + WT0_OFF;
    const float* bb = ws + B0_OFF;
    const int o0 = ob * 8;
    float acc[8];
#pragma unroll
    for (int i = 0; i < 8; ++i) acc[i] = bb[o0 + i];
    const float* hrow = hA + k * 69;
    for (int c = 0; c < C0; ++c) {
      float h = hrow[c];
      const float4 w0 = *(const float4*)(Wt + c * H1 + o0);
      const float4 w1 = *(const float4*)(Wt + c * H1 + o0 + 4);
      acc[0] = fmaf(h, w0.x, acc[0]); acc[1] = fmaf(h, w0.y, acc[1]);
      acc[2] = fmaf(h, w0.z, acc[2]); acc[3] = fmaf(h, w0.w, acc[3]);
      acc[4] = fmaf(h, w1.x, acc[4]); acc[5] = fmaf(h, w1.y, acc[5]);
      acc[6] = fmaf(h, w1.z, acc[6]); acc[7] = fmaf(h, w1.w, acc[7]);
    }
    float* orow = hB + k * 65 + o0;
#pragma unroll
    for (int i = 0; i < 8; ++i) orow[i] = fmaxf(acc[i], 0.0f);
  }
  __syncthreads();

  // ---- layer 2: 64 -> 64 (hB -> hA, stride 65) ----
  {
    const float* Wt = ws + WT1_OFF;
    const float* bb = ws + B1_OFF;
    const int o0 = ob * 8;
    float acc[8];
#pragma unroll
    for (int i = 0; i < 8; ++i) acc[i] = bb[o0 + i];
    const float* hrow = hB + k * 65;
    for (int c = 0; c < H1; ++c) {
      float h = hrow[c];
      const float4 w0 = *(const float4*)(Wt + c * H2 + o0);
      const float4 w1 = *(const float4*)(Wt + c * H2 + o0 + 4);
      acc[0] = fmaf(h, w0.x, acc[0]); acc[1] = fmaf(h, w0.y, acc[1]);
      acc[2] = fmaf(h, w0.z, acc[2]); acc[3] = fmaf(h, w0.w, acc[3]);
      acc[4] = fmaf(h, w1.x, acc[4]); acc[5] = fmaf(h, w1.y, acc[5]);
      acc[6] = fmaf(h, w1.z, acc[6]); acc[7] = fmaf(h, w1.w, acc[7]);
    }
    float* orow = hA + k * 65 + o0;
#pragma unroll
    for (int i = 0; i < 8; ++i) orow[i] = fmaxf(acc[i], 0.0f);
  }
  __syncthreads();

  // ---- layer 3: 64 -> 128 + max over neighbors ----
  {
    const float* Wt = ws + WT2_OFF;
    const float* bb = ws + B2_OFF;
    const int o0 = ob * 16;
    float acc[16];
#pragma unroll
    for (int i = 0; i < 16; ++i) acc[i] = bb[o0 + i];
    const float* hrow = hA + k * 65;
    for (int c = 0; c < H2; ++c) {
      float h = hrow[c];
      const float4 w0 = *(const float4*)(Wt + c * H3 + o0);
      const float4 w1 = *(const float4*)(Wt + c * H3 + o0 + 4);
      const float4 w2 = *(const float4*)(Wt + c * H3 + o0 + 8);
      const float4 w3 = *(const float4*)(Wt + c * H3 + o0 + 12);
      acc[0]  = fmaf(h, w0.x, acc[0]);  acc[1]  = fmaf(h, w0.y, acc[1]);
      acc[2]  = fmaf(h, w0.z, acc[2]);  acc[3]  = fmaf(h, w0.w, acc[3]);
      acc[4]  = fmaf(h, w1.x, acc[4]);  acc[5]  = fmaf(h, w1.y, acc[5]);
      acc[6]  = fmaf(h, w1.z, acc[6]);  acc[7]  = fmaf(h, w1.w, acc[7]);
      acc[8]  = fmaf(h, w2.x, acc[8]);  acc[9]  = fmaf(h, w2.y, acc[9]);
      acc[10] = fmaf(h, w2.z, acc[10]); acc[11] = fmaf(h, w2.w, acc[11]);
      acc[12] = fmaf(h, w3.x, acc[12]); acc[13] = fmaf(h, w3.y, acc[13]);
      acc[14] = fmaf(h, w3.z, acc[14]); acc[15] = fmaf(h, w3.w, acc[15]);
    }
#pragma unroll
    for (int i = 0; i < 16; ++i) acc[i] = fmaxf(acc[i], 0.0f);
    // max over 32 neighbor slots (lanes differing in bits 0..4)
#pragma unroll
    for (int m = 1; m < 32; m <<= 1) {
#pragma unroll
      for (int i = 0; i < 16; ++i) {
        float o = __shfl_xor(acc[i], m);
        acc[i] = fmaxf(acc[i], o);
      }
    }
    if (k == 0) {
      float* op = outf + srow * H3 + o0;
      *(float4*)(op + 0)  = make_float4(acc[0],  acc[1],  acc[2],  acc[3]);
      *(float4*)(op + 4)  = make_float4(acc[4],  acc[5],  acc[6],  acc[7]);
      *(float4*)(op + 8)  = make_float4(acc[8],  acc[9],  acc[10], acc[11]);
      *(float4*)(op + 12) = make_float4(acc[12], acc[13], acc[14], acc[15]);
    }
  }
}

extern "C" void kernel_launch(void* const* d_in, const int* in_sizes, int n_in,
                              void* d_out, int out_size, void* d_ws, size_t ws_size,
                              hipStream_t stream) {
  const float* xyz  = (const float*)d_in[0];
  const float* feat = (const float*)d_in[1];
  const float* W0 = (const float*)d_in[2];
  const float* g0 = (const float*)d_in[3];
  const float* be0 = (const float*)d_in[4];
  const float* m0 = (const float*)d_in[5];
  const float* v0 = (const float*)d_in[6];
  const float* W1 = (const float*)d_in[7];
  const float* g1 = (const float*)d_in[8];
  const float* be1 = (const float*)d_in[9];
  const float* m1 = (const float*)d_in[10];
  const float* v1 = (const float*)d_in[11];
  const float* W2 = (const float*)d_in[12];
  const float* g2 = (const float*)d_in[13];
  const float* be2 = (const float*)d_in[14];
  const float* m2 = (const float*)d_in[15];
  const float* v2 = (const float*)d_in[16];

  float* out = (float*)d_out;               // [B,S,3] then [B,S,128]
  float* ws = (float*)d_ws;
  int* fpsidx = (int*)(ws + FPS_OFF);
  float* outfeat = out + (size_t)NBATCH * NS * 3;

  fold_kernel<<<(B2_OFF + H3 + 255) / 256, 256, 0, stream>>>(
      W0, g0, be0, m0, v0, W1, g1, be1, m1, v1, W2, g2, be2, m2, v2, ws);
  fps_kernel<<<NBATCH, 1024, 0, stream>>>(xyz, out, fpsidx);
  sa_kernel<<<NBATCH * NS, 256, 0, stream>>>(xyz, feat, ws, fpsidx, out, outfeat);
}

// Round 5
// 3425.274 us; speedup vs baseline: 1.0885x; 1.0118x over previous
//
#include <hip/hip_runtime.h>
#include <cstdint>

#define NPTS 8192
#define NBATCH 4
#define NS 2048
#define NK 32
#define CIN 64
#define C0 67   // 3 + 64
#define H1 64
#define H2 64
#define H3 128
#define CAP 1024
#define BIGF 1e10f

// ws layout in floats
#define WT0_OFF 0        // 67*64
#define B0_OFF  4288     // 64
#define WT1_OFF 4352     // 64*64
#define B1_OFF  8448     // 64
#define WT2_OFF 8512     // 64*128
#define B2_OFF  16704    // 128
#define FPS_OFF 16832    // NBATCH*NS ints from here

__device__ __forceinline__ float sq3(float ax, float ay, float az) {
  // exact f32, no contraction: (ax*ax + ay*ay) + az*az
  return __fadd_rn(__fadd_rn(__fmul_rn(ax, ax), __fmul_rn(ay, ay)), __fmul_rn(az, az));
}

// ---------------- fold BN into weights (transposed [c][o]) ----------------
__global__ void fold_kernel(const float* __restrict__ W0, const float* __restrict__ g0, const float* __restrict__ be0, const float* __restrict__ m0, const float* __restrict__ v0,
                            const float* __restrict__ W1, const float* __restrict__ g1, const float* __restrict__ be1, const float* __restrict__ m1, const float* __restrict__ v1,
                            const float* __restrict__ W2, const float* __restrict__ g2, const float* __restrict__ be2, const float* __restrict__ m2, const float* __restrict__ v2,
                            float* __restrict__ ws) {
  int t = blockIdx.x * 256 + threadIdx.x;
  if (t < C0 * H1) {
    int c = t / H1, o = t - c * H1;
    float sc = g0[o] / sqrtf(v0[o] + 1e-5f);
    ws[WT0_OFF + t] = W0[o * C0 + c] * sc;
  } else if (t < B0_OFF + H1) {
    int o = t - B0_OFF;
    float sc = g0[o] / sqrtf(v0[o] + 1e-5f);
    ws[t] = be0[o] - m0[o] * sc;
  } else if (t < WT1_OFF + H1 * H2) {
    int t2 = t - WT1_OFF; int c = t2 / H2, o = t2 - c * H2;
    float sc = g1[o] / sqrtf(v1[o] + 1e-5f);
    ws[t] = W1[o * H1 + c] * sc;
  } else if (t < B1_OFF + H2) {
    int o = t - B1_OFF;
    float sc = g1[o] / sqrtf(v1[o] + 1e-5f);
    ws[t] = be1[o] - m1[o] * sc;
  } else if (t < WT2_OFF + H2 * H3) {
    int t2 = t - WT2_OFF; int c = t2 / H3, o = t2 - c * H3;
    float sc = g2[o] / sqrtf(v2[o] + 1e-5f);
    ws[t] = W2[o * H2 + c] * sc;
  } else if (t < B2_OFF + H3) {
    int o = t - B2_OFF;
    float sc = g2[o] / sqrtf(v2[o] + 1e-5f);
    ws[t] = be2[o] - m2[o] * sc;
  }
}

// ---------------- FPS: one block per batch, 512 threads, 16 pts/thread ----------------
// 2 waves/SIMD halves the replicated reduce issue; all-f32 reduce (no u64 ops);
// tie-break = (lowest wave, lowest lane, lowest j) == reference lowest-index.
__global__ __launch_bounds__(512)
void fps_kernel(const float* __restrict__ xyz, float* __restrict__ newxyz, int* __restrict__ fpsidx) {
  const int b = blockIdx.x;
  const float* px = xyz + (size_t)b * NPTS * 3;
  const int tid = threadIdx.x;
  const int lane = tid & 63;
  const int wv = tid >> 6;   // 0..7

  float X[16], Y[16], Z[16], D[16];
#pragma unroll
  for (int j = 0; j < 16; ++j) {
    int p = tid * 16 + j;
    X[j] = px[p * 3 + 0];
    Y[j] = px[p * 3 + 1];
    Z[j] = px[p * 3 + 2];
    D[j] = BIGF;
  }

  __shared__ float pD[2][8], pX[2][8], pY[2][8], pZ[2][8];
  __shared__ int pI[2][8];

  float cx = px[0], cy = px[1], cz = px[2];
  if (tid == 0) {
    fpsidx[b * NS] = 0;
    float* o = newxyz + (size_t)b * NS * 3;
    o[0] = cx; o[1] = cy; o[2] = cz;
  }

  int par = 0;
  for (int t = 1; t < NS; ++t) {
    // ---- min-dist update (exact f32, reference op order); D doubles as nd ----
#pragma unroll
    for (int j = 0; j < 16; ++j) {
      float dx = __fsub_rn(X[j], cx);
      float dy = __fsub_rn(Y[j], cy);
      float dz = __fsub_rn(Z[j], cz);
      float d = sq3(dx, dy, dz);
      D[j] = fminf(D[j], d);
    }
    // balanced fmax tree (exact max value; order-independent for non-NaN)
    float q0 = fmaxf(fmaxf(D[0], D[1]), fmaxf(D[2], D[3]));
    float q1 = fmaxf(fmaxf(D[4], D[5]), fmaxf(D[6], D[7]));
    float q2 = fmaxf(fmaxf(D[8], D[9]), fmaxf(D[10], D[11]));
    float q3 = fmaxf(fmaxf(D[12], D[13]), fmaxf(D[14], D[15]));
    float bd = fmaxf(fmaxf(q0, q1), fmaxf(q2, q3));
    // wave max + winner lane (lowest lane = lowest index range)
    float bdw = bd;
#pragma unroll
    for (int m = 1; m < 64; m <<= 1) bdw = fmaxf(bdw, __shfl_xor(bdw, m));
    unsigned long long mk = __ballot(bd == bdw);
    int wl = __ffsll(mk) - 1;
    if (lane == wl) {
      // lowest j with D[j]==bd, static indexing only
      int bj = 15;
      float sx = X[15], sy = Y[15], sz = Z[15];
#pragma unroll
      for (int j = 14; j >= 0; --j) {
        bool e = (D[j] == bdw);
        bj = e ? j : bj;
        sx = e ? X[j] : sx;
        sy = e ? Y[j] : sy;
        sz = e ? Z[j] : sz;
      }
      pD[par][wv] = bdw;
      pI[par][wv] = tid * 16 + bj;
      pX[par][wv] = sx; pY[par][wv] = sy; pZ[par][wv] = sz;
    }
    __syncthreads();
    // ---- every wave reduces the 8 wave-candidates (f32 only) ----
    float pd = pD[par][lane & 7];
    float gm = pd;
#pragma unroll
    for (int m = 1; m < 8; m <<= 1) gm = fmaxf(gm, __shfl_xor(gm, m));
    unsigned long long wm = __ballot(pd == gm) & 0xFFull;
    int ww = __ffsll(wm) - 1;   // lowest wave = lowest point-index range
    cx = pX[par][ww]; cy = pY[par][ww]; cz = pZ[par][ww];
    if (tid == 0) {
      int far = pI[par][ww];
      fpsidx[b * NS + t] = far;
      float* o = newxyz + ((size_t)b * NS + t) * 3;
      o[0] = cx; o[1] = cy; o[2] = cz;
    }
    par ^= 1;
  }
}

// ---------------- ball query + group + MLP + maxpool: one block per centroid ----------------
__global__ __launch_bounds__(256)
void sa_kernel(const float* __restrict__ xyz, const float* __restrict__ feat,
               const float* __restrict__ ws, const int* __restrict__ fpsidx,
               const float* __restrict__ newxyz, float* __restrict__ outf) {
  const int bs = blockIdx.x;
  const int b = bs >> 11;
  const int s = bs & (NS - 1);
  const int tid = threadIdx.x;

  __shared__ unsigned long long cand[CAP];
  __shared__ int cntS;
  __shared__ int sel[NK];
  __shared__ float hA[32 * 69];
  __shared__ float hB[32 * 65];

  const float* px = xyz + (size_t)b * NPTS * 3;
  const float* pf = feat + (size_t)b * NPTS * CIN;
  const size_t srow = (size_t)b * NS + s;
  const float cx = newxyz[srow * 3 + 0];
  const float cy = newxyz[srow * 3 + 1];
  const float cz = newxyz[srow * 3 + 2];

  if (tid == 0) cntS = 0;
  __syncthreads();

  // ---- phase A: ball query (reference formula, exact f32, no contraction) ----
  const float ssrc = sq3(cx, cy, cz);
  const float R2F = 0.04f;  // f32 round of f64 0.2**2 (NOT 0.2f*0.2f — 1 ulp above)
  for (int p = tid; p < NPTS; p += 256) {
    float x = px[p * 3 + 0], y = px[p * 3 + 1], z = px[p * 3 + 2];
    float sdst = sq3(x, y, z);
    float dot = __fadd_rn(__fadd_rn(__fmul_rn(cx, x), __fmul_rn(cy, y)), __fmul_rn(cz, z));
    float d = __fsub_rn(__fadd_rn(ssrc, sdst), __fmul_rn(2.0f, dot));
    d = fmaxf(d, 0.0f);
    if (d <= R2F) {
      int pos = atomicAdd(&cntS, 1);
      if (pos < CAP) cand[pos] = ((unsigned long long)__float_as_uint(d) << 32) | (unsigned long long)(unsigned)p;
    }
  }
  __syncthreads();

  // ---- phase B: select 32 smallest (tie -> lower point index) by wave 0 ----
  if (tid < 64) {
    const int cnt = min(cntS, CAP);
    unsigned long long key[CAP / 64];
#pragma unroll
    for (int r = 0; r < CAP / 64; ++r) {
      int e = r * 64 + tid;
      key[r] = (e < cnt) ? cand[e] : ~0ull;
    }
    unsigned long long thr = 0ull;  // keys are unique; extract in strictly increasing order
    int firstidx = 0;
    for (int j = 0; j < NK; ++j) {
      unsigned long long bk = ~0ull;
#pragma unroll
      for (int r = 0; r < CAP / 64; ++r) {
        unsigned long long kk = key[r];
        bool ok = (kk >= thr) && (kk < bk);
        bk = ok ? kk : bk;
      }
#pragma unroll
      for (int m = 1; m < 64; m <<= 1) {
        unsigned long long o = __shfl_xor(bk, m);
        bk = (o < bk) ? o : bk;
      }
      if (j == 0) firstidx = (int)(bk & 0xffffffffull);
      int idx = (bk == ~0ull) ? firstidx : (int)(bk & 0xffffffffull);  // pad with nearest (ref semantics)
      if (tid == 0) sel[j] = idx;
      if (bk != ~0ull) thr = bk + 1ull;
    }
  }
  __syncthreads();

  // ---- phase C: build h0 = [centered xyz(3) | feat(64)] into hA [32][69] ----
  {
    int kk = tid >> 3, j = tid & 7;
    int ip = sel[kk];
    const float* fr = pf + (size_t)ip * CIN + j * 8;
    float4 a = *(const float4*)(fr);
    float4 c4 = *(const float4*)(fr + 4);
    float* hrow = hA + kk * 69 + 3 + j * 8;
    hrow[0] = a.x;  hrow[1] = a.y;  hrow[2] = a.z;  hrow[3] = a.w;
    hrow[4] = c4.x; hrow[5] = c4.y; hrow[6] = c4.z; hrow[7] = c4.w;
  }
  if (tid < 32) {
    int ip = sel[tid];
    hA[tid * 69 + 0] = px[ip * 3 + 0] - cx;
    hA[tid * 69 + 1] = px[ip * 3 + 1] - cy;
    hA[tid * 69 + 2] = px[ip * 3 + 2] - cz;
  }
  __syncthreads();

  const int k = tid & 31;   // neighbor slot
  const int ob = tid >> 5;  // output-channel block (0..7)

  // ---- layer 1: 67 -> 64 ----
  {
    const float* Wt = ws + WT0_OFF;
    const float* bb = ws + B0_OFF;
    const int o0 = ob * 8;
    float acc[8];
#pragma unroll
    for (int i = 0; i < 8; ++i) acc[i] = bb[o0 + i];
    const float* hrow = hA + k * 69;
    for (int c = 0; c < C0; ++c) {
      float h = hrow[c];
      const float4 w0 = *(const float4*)(Wt + c * H1 + o0);
      const float4 w1 = *(const float4*)(Wt + c * H1 + o0 + 4);
      acc[0] = fmaf(h, w0.x, acc[0]); acc[1] = fmaf(h, w0.y, acc[1]);
      acc[2] = fmaf(h, w0.z, acc[2]); acc[3] = fmaf(h, w0.w, acc[3]);
      acc[4] = fmaf(h, w1.x, acc[4]); acc[5] = fmaf(h, w1.y, acc[5]);
      acc[6] = fmaf(h, w1.z, acc[6]); acc[7] = fmaf(h, w1.w, acc[7]);
    }
    float* orow = hB + k * 65 + o0;
#pragma unroll
    for (int i = 0; i < 8; ++i) orow[i] = fmaxf(acc[i], 0.0f);
  }
  __syncthreads();

  // ---- layer 2: 64 -> 64 (hB -> hA, stride 65) ----
  {
    const float* Wt = ws + WT1_OFF;
    const float* bb = ws + B1_OFF;
    const int o0 = ob * 8;
    float acc[8];
#pragma unroll
    for (int i = 0; i < 8; ++i) acc[i] = bb[o0 + i];
    const float* hrow = hB + k * 65;
    for (int c = 0; c < H1; ++c) {
      float h = hrow[c];
      const float4 w0 = *(const float4*)(Wt + c * H2 + o0);
      const float4 w1 = *(const float4*)(Wt + c * H2 + o0 + 4);
      acc[0] = fmaf(h, w0.x, acc[0]); acc[1] = fmaf(h, w0.y, acc[1]);
      acc[2] = fmaf(h, w0.z, acc[2]); acc[3] = fmaf(h, w0.w, acc[3]);
      acc[4] = fmaf(h, w1.x, acc[4]); acc[5] = fmaf(h, w1.y, acc[5]);
      acc[6] = fmaf(h, w1.z, acc[6]); acc[7] = fmaf(h, w1.w, acc[7]);
    }
    float* orow = hA + k * 65 + o0;
#pragma unroll
    for (int i = 0; i < 8; ++i) orow[i] = fmaxf(acc[i], 0.0f);
  }
  __syncthreads();

  // ---- layer 3: 64 -> 128 + max over neighbors ----
  {
    const float* Wt = ws + WT2_OFF;
    const float* bb = ws + B2_OFF;
    const int o0 = ob * 16;
    float acc[16];
#pragma unroll
    for (int i = 0; i < 16; ++i) acc[i] = bb[o0 + i];
    const float* hrow = hA + k * 65;
    for (int c = 0; c < H2; ++c) {
      float h = hrow[c];
      const float4 w0 = *(const float4*)(Wt + c * H3 + o0);
      const float4 w1 = *(const float4*)(Wt + c * H3 + o0 + 4);
      const float4 w2 = *(const float4*)(Wt + c * H3 + o0 + 8);
      const float4 w3 = *(const float4*)(Wt + c * H3 + o0 + 12);
      acc[0]  = fmaf(h, w0.x, acc[0]);  acc[1]  = fmaf(h, w0.y, acc[1]);
      acc[2]  = fmaf(h, w0.z, acc[2]);  acc[3]  = fmaf(h, w0.w, acc[3]);
      acc[4]  = fmaf(h, w1.x, acc[4]);  acc[5]  = fmaf(h, w1.y, acc[5]);
      acc[6]  = fmaf(h, w1.z, acc[6]);  acc[7]  = fmaf(h, w1.w, acc[7]);
      acc[8]  = fmaf(h, w2.x, acc[8]);  acc[9]  = fmaf(h, w2.y, acc[9]);
      acc[10] = fmaf(h, w2.z, acc[10]); acc[11] = fmaf(h, w2.w, acc[11]);
      acc[12] = fmaf(h, w3.x, acc[12]); acc[13] = fmaf(h, w3.y, acc[13]);
      acc[14] = fmaf(h, w3.z, acc[14]); acc[15] = fmaf(h, w3.w, acc[15]);
    }
#pragma unroll
    for (int i = 0; i < 16; ++i) acc[i] = fmaxf(acc[i], 0.0f);
    // max over 32 neighbor slots (lanes differing in bits 0..4)
#pragma unroll
    for (int m = 1; m < 32; m <<= 1) {
#pragma unroll
      for (int i = 0; i < 16; ++i) {
        float o = __shfl_xor(acc[i], m);
        acc[i] = fmaxf(acc[i], o);
      }
    }
    if (k == 0) {
      float* op = outf + srow * H3 + o0;
      *(float4*)(op + 0)  = make_float4(acc[0],  acc[1],  acc[2],  acc[3]);
      *(float4*)(op + 4)  = make_float4(acc[4],  acc[5],  acc[6],  acc[7]);
      *(float4*)(op + 8)  = make_float4(acc[8],  acc[9],  acc[10], acc[11]);
      *(float4*)(op + 12) = make_float4(acc[12], acc[13], acc[14], acc[15]);
    }
  }
}

extern "C" void kernel_launch(void* const* d_in, const int* in_sizes, int n_in,
                              void* d_out, int out_size, void* d_ws, size_t ws_size,
                              hipStream_t stream) {
  const float* xyz  = (const float*)d_in[0];
  const float* feat = (const float*)d_in[1];
  const float* W0 = (const float*)d_in[2];
  const float* g0 = (const float*)d_in[3];
  const float* be0 = (const float*)d_in[4];
  const float* m0 = (const float*)d_in[5];
  const float* v0 = (const float*)d_in[6];
  const float* W1 = (const float*)d_in[7];
  const float* g1 = (const float*)d_in[8];
  const float* be1 = (const float*)d_in[9];
  const float* m1 = (const float*)d_in[10];
  const float* v1 = (const float*)d_in[11];
  const float* W2 = (const float*)d_in[12];
  const float* g2 = (const float*)d_in[13];
  const float* be2 = (const float*)d_in[14];
  const float* m2 = (const float*)d_in[15];
  const float* v2 = (const float*)d_in[16];

  float* out = (float*)d_out;               // [B,S,3] then [B,S,128]
  float* ws = (float*)d_ws;
  int* fpsidx = (int*)(ws + FPS_OFF);
  float* outfeat = out + (size_t)NBATCH * NS * 3;

  fold_kernel<<<(B2_OFF + H3 + 255) / 256, 256, 0, stream>>>(
      W0, g0, be0, m0, v0, W1, g1, be1, m1, v1, W2, g2, be2, m2, v2, ws);
  fps_kernel<<<NBATCH, 512, 0, stream>>>(xyz, out, fpsidx);
  sa_kernel<<<NBATCH * NS, 256, 0, stream>>>(xyz, feat, ws, fpsidx, out, outfeat);
}

// Round 6
// 3259.514 us; speedup vs baseline: 1.1439x; 1.0509x over previous
//
#include <hip/hip_runtime.h>
#include <cstdint>

#define NPTS 8192
#define NBATCH 4
#define NS 2048
#define NK 32
#define CIN 64
#define C0 67   // 3 + 64
#define H1 64
#define H2 64
#define H3 128
#define CAP 1024
#define BIGF 1e10f

// ws layout in floats
#define WT0_OFF 0        // 67*64
#define B0_OFF  4288     // 64
#define WT1_OFF 4352     // 64*64
#define B1_OFF  8448     // 64
#define WT2_OFF 8512     // 64*128
#define B2_OFF  16704    // 128
#define FPS_OFF 16832    // NBATCH*NS ints from here

__device__ __forceinline__ float sq3(float ax, float ay, float az) {
  // exact f32, no contraction: (ax*ax + ay*ay) + az*az
  return __fadd_rn(__fadd_rn(__fmul_rn(ax, ax), __fmul_rn(ay, ay)), __fmul_rn(az, az));
}

// VALU-speed cross-lane fmax via DPP (ctrl must be an immediate)
#define DPPMAX(r, ctrl)                                                              \
  {                                                                                  \
    int _t = __builtin_amdgcn_update_dpp(__float_as_int(r), __float_as_int(r),       \
                                         (ctrl), 0xf, 0xf, true);                    \
    (r) = fmaxf((r), __int_as_float(_t));                                            \
  }

// ---------------- fold BN into weights (transposed [c][o]) ----------------
__global__ void fold_kernel(const float* __restrict__ W0, const float* __restrict__ g0, const float* __restrict__ be0, const float* __restrict__ m0, const float* __restrict__ v0,
                            const float* __restrict__ W1, const float* __restrict__ g1, const float* __restrict__ be1, const float* __restrict__ m1, const float* __restrict__ v1,
                            const float* __restrict__ W2, const float* __restrict__ g2, const float* __restrict__ be2, const float* __restrict__ m2, const float* __restrict__ v2,
                            float* __restrict__ ws) {
  int t = blockIdx.x * 256 + threadIdx.x;
  if (t < C0 * H1) {
    int c = t / H1, o = t - c * H1;
    float sc = g0[o] / sqrtf(v0[o] + 1e-5f);
    ws[WT0_OFF + t] = W0[o * C0 + c] * sc;
  } else if (t < B0_OFF + H1) {
    int o = t - B0_OFF;
    float sc = g0[o] / sqrtf(v0[o] + 1e-5f);
    ws[t] = be0[o] - m0[o] * sc;
  } else if (t < WT1_OFF + H1 * H2) {
    int t2 = t - WT1_OFF; int c = t2 / H2, o = t2 - c * H2;
    float sc = g1[o] / sqrtf(v1[o] + 1e-5f);
    ws[t] = W1[o * H1 + c] * sc;
  } else if (t < B1_OFF + H2) {
    int o = t - B1_OFF;
    float sc = g1[o] / sqrtf(v1[o] + 1e-5f);
    ws[t] = be1[o] - m1[o] * sc;
  } else if (t < WT2_OFF + H2 * H3) {
    int t2 = t - WT2_OFF; int c = t2 / H3, o = t2 - c * H3;
    float sc = g2[o] / sqrtf(v2[o] + 1e-5f);
    ws[t] = W2[o * H2 + c] * sc;
  } else if (t < B2_OFF + H3) {
    int o = t - B2_OFF;
    float sc = g2[o] / sqrtf(v2[o] + 1e-5f);
    ws[t] = be2[o] - m2[o] * sc;
  }
}

// ---------------- FPS: one block per batch, 512 threads, 16 pts/thread ----------------
// DPP-based reduces (no ds_bpermute/ds_swizzle on the serial chain); winner fields
// recovered via v_readlane from candidate lanes (kills the 2nd dependent ds_read).
// Tie-break: (lowest wave, lowest lane, lowest j) == reference lowest-index. Exact.
__global__ __launch_bounds__(512)
void fps_kernel(const float* __restrict__ xyz, float* __restrict__ newxyz, int* __restrict__ fpsidx) {
  const int b = blockIdx.x;
  const float* px = xyz + (size_t)b * NPTS * 3;
  const int tid = threadIdx.x;
  const int lane = tid & 63;
  const int wv = tid >> 6;   // 0..7

  float X[16], Y[16], Z[16], D[16];
#pragma unroll
  for (int j = 0; j < 16; ++j) {
    int p = tid * 16 + j;
    X[j] = px[p * 3 + 0];
    Y[j] = px[p * 3 + 1];
    Z[j] = px[p * 3 + 2];
    D[j] = BIGF;
  }

  // candidate slots: [parity][wave][8 floats: d, idx_bits, x, y, z, pad...]
  __shared__ float cnd[2][8][8];

  float cx = px[0], cy = px[1], cz = px[2];
  if (tid == 0) {
    fpsidx[b * NS] = 0;
    float* o = newxyz + (size_t)b * NS * 3;
    o[0] = cx; o[1] = cy; o[2] = cz;
  }

  int par = 0;
  for (int t = 1; t < NS; ++t) {
    // ---- min-dist update (exact f32, reference op order); D doubles as nd ----
#pragma unroll
    for (int j = 0; j < 16; ++j) {
      float dx = __fsub_rn(X[j], cx);
      float dy = __fsub_rn(Y[j], cy);
      float dz = __fsub_rn(Z[j], cz);
      float d = sq3(dx, dy, dz);
      D[j] = fminf(D[j], d);
    }
    // balanced fmax tree (exact max value; order-independent for non-NaN)
    float q0 = fmaxf(fmaxf(D[0], D[1]), fmaxf(D[2], D[3]));
    float q1 = fmaxf(fmaxf(D[4], D[5]), fmaxf(D[6], D[7]));
    float q2 = fmaxf(fmaxf(D[8], D[9]), fmaxf(D[10], D[11]));
    float q3 = fmaxf(fmaxf(D[12], D[13]), fmaxf(D[14], D[15]));
    float bd = fmaxf(fmaxf(q0, q1), fmaxf(q2, q3));

    // ---- wave max via DPP: 4x row_ror -> row max; bcast15/31 -> lane63 = wave max ----
    float r = bd;
    DPPMAX(r, 0x121);  // row_ror:1
    DPPMAX(r, 0x122);  // row_ror:2
    DPPMAX(r, 0x124);  // row_ror:4
    DPPMAX(r, 0x128);  // row_ror:8   -> every lane holds its 16-lane row max
    DPPMAX(r, 0x142);  // row_bcast15 -> lane31=max(r0,r1), lane63=max(r2,r3)
    DPPMAX(r, 0x143);  // row_bcast31 -> lane63 = wave max
    float bdw = __int_as_float(__builtin_amdgcn_readlane(__float_as_int(r), 63));

    unsigned long long mk = __ballot(bd == bdw);
    int wl = __ffsll(mk) - 1;   // lowest lane = lowest index range
    if (lane == wl) {
      // lowest j with D[j]==bdw, static indexing only
      int bj = 15;
      float sx = X[15], sy = Y[15], sz = Z[15];
#pragma unroll
      for (int j = 14; j >= 0; --j) {
        bool e = (D[j] == bdw);
        bj = e ? j : bj;
        sx = e ? X[j] : sx;
        sy = e ? Y[j] : sy;
        sz = e ? Z[j] : sz;
      }
      float* c = &cnd[par][wv][0];
      c[0] = bdw;
      c[1] = __int_as_float(tid * 16 + bj);
      c[2] = sx; c[3] = sy; c[4] = sz;
    }
    __syncthreads();

    // ---- cross-wave reduce: lanes mirror the 8 candidates, DPP ring-max over 16 ----
    const int ci = lane & 7;
    float4 cd = *(const float4*)&cnd[par][ci][0];   // d, idx_bits, x, y
    float czv = cnd[par][ci][4];
    float rr = cd.x;
    DPPMAX(rr, 0x121);
    DPPMAX(rr, 0x122);
    DPPMAX(rr, 0x124);
    DPPMAX(rr, 0x128);   // every lane: max over the 8 candidates (16-ring w/ duplicates)
    unsigned long long wm = __ballot(cd.x == rr) & 0xFFull;
    int ww = __ffsll(wm) - 1;   // lowest wave = lowest point-index range
    cx = __int_as_float(__builtin_amdgcn_readlane(__float_as_int(cd.z), ww));
    cy = __int_as_float(__builtin_amdgcn_readlane(__float_as_int(cd.w), ww));
    cz = __int_as_float(__builtin_amdgcn_readlane(__float_as_int(czv), ww));
    if (tid == 0) {
      int far = __builtin_amdgcn_readlane(__float_as_int(cd.y), ww);
      fpsidx[b * NS + t] = far;
      float* o = newxyz + ((size_t)b * NS + t) * 3;
      o[0] = cx; o[1] = cy; o[2] = cz;
    }
    par ^= 1;
  }
}

// ---------------- ball query + group + MLP + maxpool: one block per centroid ----------------
__global__ __launch_bounds__(256)
void sa_kernel(const float* __restrict__ xyz, const float* __restrict__ feat,
               const float* __restrict__ ws, const int* __restrict__ fpsidx,
               const float* __restrict__ newxyz, float* __restrict__ outf) {
  const int bs = blockIdx.x;
  const int b = bs >> 11;
  const int s = bs & (NS - 1);
  const int tid = threadIdx.x;

  __shared__ unsigned long long cand[CAP];
  __shared__ int cntS;
  __shared__ int sel[NK];
  __shared__ float hA[32 * 69];
  __shared__ float hB[32 * 65];

  const float* px = xyz + (size_t)b * NPTS * 3;
  const float* pf = feat + (size_t)b * NPTS * CIN;
  const size_t srow = (size_t)b * NS + s;
  const float cx = newxyz[srow * 3 + 0];
  const float cy = newxyz[srow * 3 + 1];
  const float cz = newxyz[srow * 3 + 2];

  if (tid == 0) cntS = 0;
  __syncthreads();

  // ---- phase A: ball query (reference formula, exact f32, no contraction) ----
  const float ssrc = sq3(cx, cy, cz);
  const float R2F = 0.04f;  // f32 round of f64 0.2**2 (NOT 0.2f*0.2f — 1 ulp above)
  for (int p = tid; p < NPTS; p += 256) {
    float x = px[p * 3 + 0], y = px[p * 3 + 1], z = px[p * 3 + 2];
    float sdst = sq3(x, y, z);
    float dot = __fadd_rn(__fadd_rn(__fmul_rn(cx, x), __fmul_rn(cy, y)), __fmul_rn(cz, z));
    float d = __fsub_rn(__fadd_rn(ssrc, sdst), __fmul_rn(2.0f, dot));
    d = fmaxf(d, 0.0f);
    if (d <= R2F) {
      int pos = atomicAdd(&cntS, 1);
      if (pos < CAP) cand[pos] = ((unsigned long long)__float_as_uint(d) << 32) | (unsigned long long)(unsigned)p;
    }
  }
  __syncthreads();

  // ---- phase B: select 32 smallest (tie -> lower point index) by wave 0 ----
  if (tid < 64) {
    const int cnt = min(cntS, CAP);
    unsigned long long key[CAP / 64];
#pragma unroll
    for (int r = 0; r < CAP / 64; ++r) {
      int e = r * 64 + tid;
      key[r] = (e < cnt) ? cand[e] : ~0ull;
    }
    unsigned long long thr = 0ull;  // keys are unique; extract in strictly increasing order
    int firstidx = 0;
    for (int j = 0; j < NK; ++j) {
      unsigned long long bk = ~0ull;
#pragma unroll
      for (int r = 0; r < CAP / 64; ++r) {
        unsigned long long kk = key[r];
        bool ok = (kk >= thr) && (kk < bk);
        bk = ok ? kk : bk;
      }
#pragma unroll
      for (int m = 1; m < 64; m <<= 1) {
        unsigned long long o = __shfl_xor(bk, m);
        bk = (o < bk) ? o : bk;
      }
      if (j == 0) firstidx = (int)(bk & 0xffffffffull);
      int idx = (bk == ~0ull) ? firstidx : (int)(bk & 0xffffffffull);  // pad with nearest (ref semantics)
      if (tid == 0) sel[j] = idx;
      if (bk != ~0ull) thr = bk + 1ull;
    }
  }
  __syncthreads();

  // ---- phase C: build h0 = [centered xyz(3) | feat(64)] into hA [32][69] ----
  {
    int kk = tid >> 3, j = tid & 7;
    int ip = sel[kk];
    const float* fr = pf + (size_t)ip * CIN + j * 8;
    float4 a = *(const float4*)(fr);
    float4 c4 = *(const float4*)(fr + 4);
    float* hrow = hA + kk * 69 + 3 + j * 8;
    hrow[0] = a.x;  hrow[1] = a.y;  hrow[2] = a.z;  hrow[3] = a.w;
    hrow[4] = c4.x; hrow[5] = c4.y; hrow[6] = c4.z; hrow[7] = c4.w;
  }
  if (tid < 32) {
    int ip = sel[tid];
    hA[tid * 69 + 0] = px[ip * 3 + 0] - cx;
    hA[tid * 69 + 1] = px[ip * 3 + 1] - cy;
    hA[tid * 69 + 2] = px[ip * 3 + 2] - cz;
  }
  __syncthreads();

  const int k = tid & 31;   // neighbor slot
  const int ob = tid >> 5;  // output-channel block (0..7)

  // ---- layer 1: 67 -> 64 ----
  {
    const float* Wt = ws + WT0_OFF;
    const float* bb = ws + B0_OFF;
    const int o0 = ob * 8;
    float acc[8];
#pragma unroll
    for (int i = 0; i < 8; ++i) acc[i] = bb[o0 + i];
    const float* hrow = hA + k * 69;
    for (int c = 0; c < C0; ++c) {
      float h = hrow[c];
      const float4 w0 = *(const float4*)(Wt + c * H1 + o0);
      const float4 w1 = *(const float4*)(Wt + c * H1 + o0 + 4);
      acc[0] = fmaf(h, w0.x, acc[0]); acc[1] = fmaf(h, w0.y, acc[1]);
      acc[2] = fmaf(h, w0.z, acc[2]); acc[3] = fmaf(h, w0.w, acc[3]);
      acc[4] = fmaf(h, w1.x, acc[4]); acc[5] = fmaf(h, w1.y, acc[5]);
      acc[6] = fmaf(h, w1.z, acc[6]); acc[7] = fmaf(h, w1.w, acc[7]);
    }
    float* orow = hB + k * 65 + o0;
#pragma unroll
    for (int i = 0; i < 8; ++i) orow[i] = fmaxf(acc[i], 0.0f);
  }
  __syncthreads();

  // ---- layer 2: 64 -> 64 (hB -> hA, stride 65) ----
  {
    const float* Wt = ws + WT1_OFF;
    const float* bb = ws + B1_OFF;
    const int o0 = ob * 8;
    float acc[8];
#pragma unroll
    for (int i = 0; i < 8; ++i) acc[i] = bb[o0 + i];
    const float* hrow = hB + k * 65;
    for (int c = 0; c < H1; ++c) {
      float h = hrow[c];
      const float4 w0 = *(const float4*)(Wt + c * H2 + o0);
      const float4 w1 = *(const float4*)(Wt + c * H2 + o0 + 4);
      acc[0] = fmaf(h, w0.x, acc[0]); acc[1] = fmaf(h, w0.y, acc[1]);
      acc[2] = fmaf(h, w0.z, acc[2]); acc[3] = fmaf(h, w0.w, acc[3]);
      acc[4] = fmaf(h, w1.x, acc[4]); acc[5] = fmaf(h, w1.y, acc[5]);
      acc[6] = fmaf(h, w1.z, acc[6]); acc[7] = fmaf(h, w1.w, acc[7]);
    }
    float* orow = hA + k * 65 + o0;
#pragma unroll
    for (int i = 0; i < 8; ++i) orow[i] = fmaxf(acc[i], 0.0f);
  }
  __syncthreads();

  // ---- layer 3: 64 -> 128 + max over neighbors ----
  {
    const float* Wt = ws + WT2_OFF;
    const float* bb = ws + B2_OFF;
    const int o0 = ob * 16;
    float acc[16];
#pragma unroll
    for (int i = 0; i < 16; ++i) acc[i] = bb[o0 + i];
    const float* hrow = hA + k * 65;
    for (int c = 0; c < H2; ++c) {
      float h = hrow[c];
      const float4 w0 = *(const float4*)(Wt + c * H3 + o0);
      const float4 w1 = *(const float4*)(Wt + c * H3 + o0 + 4);
      const float4 w2 = *(const float4*)(Wt + c * H3 + o0 + 8);
      const float4 w3 = *(const float4*)(Wt + c * H3 + o0 + 12);
      acc[0]  = fmaf(h, w0.x, acc[0]);  acc[1]  = fmaf(h, w0.y, acc[1]);
      acc[2]  = fmaf(h, w0.z, acc[2]);  acc[3]  = fmaf(h, w0.w, acc[3]);
      acc[4]  = fmaf(h, w1.x, acc[4]);  acc[5]  = fmaf(h, w1.y, acc[5]);
      acc[6]  = fmaf(h, w1.z, acc[6]);  acc[7]  = fmaf(h, w1.w, acc[7]);
      acc[8]  = fmaf(h, w2.x, acc[8]);  acc[9]  = fmaf(h, w2.y, acc[9]);
      acc[10] = fmaf(h, w2.z, acc[10]); acc[11] = fmaf(h, w2.w, acc[11]);
      acc[12] = fmaf(h, w3.x, acc[12]); acc[13] = fmaf(h, w3.y, acc[13]);
      acc[14] = fmaf(h, w3.z, acc[14]); acc[15] = fmaf(h, w3.w, acc[15]);
    }
#pragma unroll
    for (int i = 0; i < 16; ++i) acc[i] = fmaxf(acc[i], 0.0f);
    // max over 32 neighbor slots (lanes differing in bits 0..4)
#pragma unroll
    for (int m = 1; m < 32; m <<= 1) {
#pragma unroll
      for (int i = 0; i < 16; ++i) {
        float o = __shfl_xor(acc[i], m);
        acc[i] = fmaxf(acc[i], o);
      }
    }
    if (k == 0) {
      float* op = outf + srow * H3 + o0;
      *(float4*)(op + 0)  = make_float4(acc[0],  acc[1],  acc[2],  acc[3]);
      *(float4*)(op + 4)  = make_float4(acc[4],  acc[5],  acc[6],  acc[7]);
      *(float4*)(op + 8)  = make_float4(acc[8],  acc[9],  acc[10], acc[11]);
      *(float4*)(op + 12) = make_float4(acc[12], acc[13], acc[14], acc[15]);
    }
  }
}

extern "C" void kernel_launch(void* const* d_in, const int* in_sizes, int n_in,
                              void* d_out, int out_size, void* d_ws, size_t ws_size,
                              hipStream_t stream) {
  const float* xyz  = (const float*)d_in[0];
  const float* feat = (const float*)d_in[1];
  const float* W0 = (const float*)d_in[2];
  const float* g0 = (const float*)d_in[3];
  const float* be0 = (const float*)d_in[4];
  const float* m0 = (const float*)d_in[5];
  const float* v0 = (const float*)d_in[6];
  const float* W1 = (const float*)d_in[7];
  const float* g1 = (const float*)d_in[8];
  const float* be1 = (const float*)d_in[9];
  const float* m1 = (const float*)d_in[10];
  const float* v1 = (const float*)d_in[11];
  const float* W2 = (const float*)d_in[12];
  const float* g2 = (const float*)d_in[13];
  const float* be2 = (const float*)d_in[14];
  const float* m2 = (const float*)d_in[15];
  const float* v2 = (const float*)d_in[16];

  float* out = (float*)d_out;               // [B,S,3] then [B,S,128]
  float* ws = (float*)d_ws;
  int* fpsidx = (int*)(ws + FPS_OFF);
  float* outfeat = out + (size_t)NBATCH * NS * 3;

  fold_kernel<<<(B2_OFF + H3 + 255) / 256, 256, 0, stream>>>(
      W0, g0, be0, m0, v0, W1, g1, be1, m1, v1, W2, g2, be2, m2, v2, ws);
  fps_kernel<<<NBATCH, 512, 0, stream>>>(xyz, out, fpsidx);
  sa_kernel<<<NBATCH * NS, 256, 0, stream>>>(xyz, feat, ws, fpsidx, out, outfeat);
}